// Round 1
// baseline (628.661 us; speedup 1.0000x reference)
//
#include <hip/hip_runtime.h>

// Problem constants (QuadraticAttention): B=2, T=2048, D_MODEL=1024, H=16, d=64
#define TSEQ   2048
#define DM     1024
#define NHEAD  16
#define DH     64
#define BATCH  2
#define MR     (BATCH * TSEQ)   // 4096 rows
#define CH     64               // attention chunk length
#define NC     (TSEQ / CH)      // 32 chunks per sequence

// ---------------------------------------------------------------------------
// Generic fp32 tiled GEMM: C[M,N] = A[M,K] @ B[K,N] (all row-major).
// 64x64 tile, BK=16, 256 threads, 4x4 microtile/thread, float4 LDS reads.
// ---------------------------------------------------------------------------
__global__ __launch_bounds__(256) void gemm64(const float* __restrict__ A,
                                              const float* __restrict__ B,
                                              float* __restrict__ C,
                                              int M, int N, int K) {
  __shared__ __align__(16) float As[16][68];  // [k][m], +4 pad keeps f4 align, kills conflicts
  __shared__ __align__(16) float Bs[16][68];  // [k][n]
  const int tid = threadIdx.x;
  const int tx = tid & 15, ty = tid >> 4;
  const int row0 = blockIdx.y * 64, col0 = blockIdx.x * 64;
  const float* Ab = A + (size_t)row0 * K;
  const float* Bb = B + col0;
  const int ar = tid >> 2, ac4 = (tid & 3) * 4;    // A stage: row 0..63, col quad
  const int br = tid >> 4, bc4 = (tid & 15) * 4;   // B stage: row 0..15, col quad
  float acc[4][4] = {};

  for (int k0 = 0; k0 < K; k0 += 16) {
    float4 av = *(const float4*)(Ab + (size_t)ar * K + k0 + ac4);
    float4 bv = *(const float4*)(Bb + (size_t)(k0 + br) * N + bc4);
    As[ac4 + 0][ar] = av.x;
    As[ac4 + 1][ar] = av.y;
    As[ac4 + 2][ar] = av.z;
    As[ac4 + 3][ar] = av.w;
    *(float4*)&Bs[br][bc4] = bv;
    __syncthreads();
#pragma unroll
    for (int kk = 0; kk < 16; ++kk) {
      float4 a4 = *(const float4*)&As[kk][ty * 4];
      float4 b4 = *(const float4*)&Bs[kk][tx * 4];
      const float a[4] = {a4.x, a4.y, a4.z, a4.w};
      const float b[4] = {b4.x, b4.y, b4.z, b4.w};
#pragma unroll
      for (int i = 0; i < 4; ++i)
#pragma unroll
        for (int j = 0; j < 4; ++j)
          acc[i][j] = fmaf(a[i], b[j], acc[i][j]);
    }
    __syncthreads();
  }
  float* Cb = C + (size_t)row0 * N + col0;
#pragma unroll
  for (int i = 0; i < 4; ++i) {
    float4 o = {acc[i][0], acc[i][1], acc[i][2], acc[i][3]};
    *(float4*)(Cb + (size_t)(ty * 4 + i) * N + tx * 4) = o;
  }
}

// ---------------------------------------------------------------------------
// Phase A: per (b,h,chunk) M_c[i][j] = sum_{s in chunk} k_s[i] * v_s[j]
// (64x64 state contribution). Written to S at [(b*H+h)*NC + c].
// ---------------------------------------------------------------------------
__global__ __launch_bounds__(256) void chunk_kv(const float* __restrict__ K_,
                                                const float* __restrict__ V_,
                                                float* __restrict__ S) {
  const int c = blockIdx.x, h = blockIdx.y, b = blockIdx.z;
  __shared__ __align__(16) float Ks[CH][DH];
  __shared__ __align__(16) float Vs[CH][DH];
  const int tid = threadIdx.x;
  const size_t rowbase = ((size_t)(b * TSEQ + c * CH)) * DM + h * DH;
#pragma unroll
  for (int it = 0; it < 4; ++it) {
    int idx = tid + 256 * it;              // float4 index 0..1023
    int s = idx >> 4, i4 = (idx & 15) * 4;
    *(float4*)&Ks[s][i4] = *(const float4*)(K_ + rowbase + (size_t)s * DM + i4);
    *(float4*)&Vs[s][i4] = *(const float4*)(V_ + rowbase + (size_t)s * DM + i4);
  }
  __syncthreads();
  const int i0 = (tid >> 4) * 4, j0 = (tid & 15) * 4;
  float acc[4][4] = {};
  for (int s = 0; s < CH; ++s) {
    float a[4], bv[4];
#pragma unroll
    for (int x = 0; x < 4; ++x) { a[x] = Ks[s][i0 + x]; bv[x] = Vs[s][j0 + x]; }
#pragma unroll
    for (int i = 0; i < 4; ++i)
#pragma unroll
      for (int j = 0; j < 4; ++j)
        acc[i][j] = fmaf(a[i], bv[j], acc[i][j]);
  }
  float* out = S + ((size_t)((b * NHEAD + h) * NC + c)) * (DH * DH);
#pragma unroll
  for (int i = 0; i < 4; ++i) {
    float4 o = {acc[i][0], acc[i][1], acc[i][2], acc[i][3]};
    *(float4*)(out + (size_t)(i0 + i) * DH + j0) = o;
  }
}

// ---------------------------------------------------------------------------
// Phase B: in-place EXCLUSIVE prefix sum of the 32 chunk states per (b,h).
// One block per (b,h); thread owns 16 strided elements of the 64x64 state.
// ---------------------------------------------------------------------------
__global__ __launch_bounds__(256) void scan_states(float* __restrict__ S) {
  const int bh = blockIdx.x;
  float* base = S + (size_t)bh * NC * (DH * DH);
  const int tid = threadIdx.x;
  float run[16];
#pragma unroll
  for (int e = 0; e < 16; ++e) run[e] = 0.f;
  for (int c = 0; c < NC; ++c) {
    float* p = base + (size_t)c * (DH * DH);
#pragma unroll
    for (int e = 0; e < 16; ++e) {
      const int idx = tid + 256 * e;
      float tmp = p[idx];
      p[idx] = run[e];      // exclusive: sum of chunks < c
      run[e] += tmp;
    }
  }
}

// ---------------------------------------------------------------------------
// Phase C: out_t = q_t @ S_c  +  sum_{s in chunk, s<t} (q_t . k_s) v_s
// One block per (b,h,chunk). LDS = 4 * 16 KB = 64 KB exactly.
// Ss holds the state first, then is reused for the masked score matrix P.
// ---------------------------------------------------------------------------
__global__ __launch_bounds__(256) void intra_attn(const float* __restrict__ Q_,
                                                  const float* __restrict__ K_,
                                                  const float* __restrict__ V_,
                                                  const float* __restrict__ S,
                                                  float* __restrict__ O_) {
  const int c = blockIdx.x, h = blockIdx.y, b = blockIdx.z;
  __shared__ __align__(16) float Qs[CH][DH];
  __shared__ __align__(16) float Ks[CH][DH];
  __shared__ __align__(16) float Vs[CH][DH];
  __shared__ __align__(16) float Ss[DH][DH];   // state -> then P
  const int tid = threadIdx.x;
  const size_t rowbase = ((size_t)(b * TSEQ + c * CH)) * DM + h * DH;
  const float* Sb = S + ((size_t)((b * NHEAD + h) * NC + c)) * (DH * DH);
#pragma unroll
  for (int it = 0; it < 4; ++it) {
    int idx = tid + 256 * it;
    int s = idx >> 4, i4 = (idx & 15) * 4;
    size_t g = rowbase + (size_t)s * DM + i4;
    *(float4*)&Qs[s][i4] = *(const float4*)(Q_ + g);
    *(float4*)&Ks[s][i4] = *(const float4*)(K_ + g);
    *(float4*)&Vs[s][i4] = *(const float4*)(V_ + g);
    *(float4*)&Ss[s][i4] = *(const float4*)(Sb + (size_t)idx * 4);
  }
  __syncthreads();
  const int t0 = (tid >> 4) * 4, j0 = (tid & 15) * 4;

  // (1) state term: oacc[t][j] = sum_i Q[t][i] * S[i][j]
  float oacc[4][4] = {};
  for (int i = 0; i < DH; ++i) {
    float a[4], bb[4];
#pragma unroll
    for (int x = 0; x < 4; ++x) { a[x] = Qs[t0 + x][i]; bb[x] = Ss[i][j0 + x]; }
#pragma unroll
    for (int ii = 0; ii < 4; ++ii)
#pragma unroll
      for (int jj = 0; jj < 4; ++jj)
        oacc[ii][jj] = fmaf(a[ii], bb[jj], oacc[ii][jj]);
  }
  // (2) scores: pacc[t][s] = sum_i Q[t][i] * K[s][i]   (s indexed by j0)
  float pacc[4][4] = {};
  for (int i = 0; i < DH; ++i) {
    float a[4], bb[4];
#pragma unroll
    for (int x = 0; x < 4; ++x) { a[x] = Qs[t0 + x][i]; bb[x] = Ks[j0 + x][i]; }
#pragma unroll
    for (int ii = 0; ii < 4; ++ii)
#pragma unroll
      for (int jj = 0; jj < 4; ++jj)
        pacc[ii][jj] = fmaf(a[ii], bb[jj], pacc[ii][jj]);
  }
  __syncthreads();   // everyone finished reading the state from Ss
  // strict causal mask: keep s < t only
#pragma unroll
  for (int ii = 0; ii < 4; ++ii)
#pragma unroll
    for (int jj = 0; jj < 4; ++jj)
      Ss[t0 + ii][j0 + jj] = (j0 + jj < t0 + ii) ? pacc[ii][jj] : 0.f;
  __syncthreads();
  // (3) oacc[t][j] += sum_s P[t][s] * V[s][j]
  for (int s = 0; s < CH; ++s) {
    float a[4], bb[4];
#pragma unroll
    for (int x = 0; x < 4; ++x) { a[x] = Ss[t0 + x][s]; bb[x] = Vs[s][j0 + x]; }
#pragma unroll
    for (int ii = 0; ii < 4; ++ii)
#pragma unroll
      for (int jj = 0; jj < 4; ++jj)
        oacc[ii][jj] = fmaf(a[ii], bb[jj], oacc[ii][jj]);
  }
#pragma unroll
  for (int ii = 0; ii < 4; ++ii) {
    float4 o = {oacc[ii][0], oacc[ii][1], oacc[ii][2], oacc[ii][3]};
    *(float4*)(O_ + rowbase + (size_t)(t0 + ii) * DM + j0) = o;
  }
}

// ---------------------------------------------------------------------------
extern "C" void kernel_launch(void* const* d_in, const int* in_sizes, int n_in,
                              void* d_out, int out_size, void* d_ws, size_t ws_size,
                              hipStream_t stream) {
  const float* x  = (const float*)d_in[0];
  const float* Wq = (const float*)d_in[1];
  const float* Wk = (const float*)d_in[2];
  const float* Wv = (const float*)d_in[3];
  const float* Wo = (const float*)d_in[4];
  float* out = (float*)d_out;

  const size_t NFL = (size_t)MR * DM;  // 4,194,304 floats (16 MB)
  float* q  = (float*)d_ws;            // [MR, DM]
  float* k  = q + NFL;                 // [MR, DM]
  float* v  = k + NFL;                 // [MR, DM]
  float* S  = v + NFL;                 // [B*H*NC, 64*64] == NFL floats
  float* ao = S + NFL;                 // [MR, DM] attention output
  // total ws use: 5 * 16 MB = 80 MB

  dim3 g(DM / 64, MR / 64);  // (16, 64)
  gemm64<<<g, 256, 0, stream>>>(x, Wq, q, MR, DM, DM);
  gemm64<<<g, 256, 0, stream>>>(x, Wk, k, MR, DM, DM);
  gemm64<<<g, 256, 0, stream>>>(x, Wv, v, MR, DM, DM);
  chunk_kv<<<dim3(NC, NHEAD, BATCH), 256, 0, stream>>>(k, v, S);
  scan_states<<<BATCH * NHEAD, 256, 0, stream>>>(S);
  intra_attn<<<dim3(NC, NHEAD, BATCH), 256, 0, stream>>>(q, k, v, S, ao);
  gemm64<<<g, 256, 0, stream>>>(ao, Wo, out, MR, DM, DM);
}

// Round 2
// 241.252 us; speedup vs baseline: 2.6058x; 2.6058x over previous
//
#include <hip/hip_runtime.h>
#include <hip/hip_bf16.h>

// Problem constants (QuadraticAttention): B=2, T=2048, D_MODEL=1024, H=16, d=64
#define TSEQ   2048
#define DM     1024
#define NHEAD  16
#define DH     64
#define BATCH  2
#define MR     (BATCH * TSEQ)   // 4096 rows
#define CH     64               // attention chunk length
#define NC     (TSEQ / CH)      // 32 chunks per sequence
#define QKVLD  (3 * DM)         // 3072: q|k|v packed per token row

typedef __attribute__((ext_vector_type(8))) short bf16x8;
typedef __attribute__((ext_vector_type(4))) float f32x4;

// ---------------------------------------------------------------------------
// async global->LDS, 16 bytes per lane. LDS dest must be wave-uniform base +
// lane*16 (it is: we pass &lds[tid*8shorts] with waves contiguous in tid).
// ---------------------------------------------------------------------------
__device__ __forceinline__ void stage16(const void* g, void* l) {
  __builtin_amdgcn_global_load_lds(
      (const __attribute__((address_space(1))) void*)g,
      (__attribute__((address_space(3))) void*)l, 16, 0, 0);
}

// ---------------------------------------------------------------------------
// bf16 MFMA GEMM (m97 structure): C[M,N] = A[M,K] @ B[K,N], fp32 out.
// A: bf16 row-major [M,K] (lda=K). Bt: bf16 [N,K] (B transposed).
// 128x128 tile, BK=32, 256 threads = 4 waves (2x2), 4x4 MFMA tiles per wave.
// ---------------------------------------------------------------------------
__global__ __launch_bounds__(256) void gemm_bf16(const short* __restrict__ A,
                                                 const short* __restrict__ Bt,
                                                 float* __restrict__ C,
                                                 int M, int N, int K, int ldc) {
  __shared__ short As[128][32];  // [m][k]  8 KB
  __shared__ short Bs[128][32];  // [n][k]  8 KB
  const int tid = threadIdx.x;
  const int lane = tid & 63, wid = tid >> 6;
  const int wave_m = wid >> 1, wave_n = wid & 1;   // 2x2 waves of 64x64
  const int row0 = blockIdx.y * 128, col0 = blockIdx.x * 128;

  // staging thread map: r = tid/4 (0..63), kq = (tid%4)*8 -> 16B each
  const int sr = tid >> 2, sk = (tid & 3) * 8;
  const short* Ag0 = A + (size_t)(row0 + sr) * K + sk;
  const short* Bg0 = Bt + (size_t)(col0 + sr) * K + sk;
  short* AsL = &As[0][0] + tid * 8;   // byte offset tid*16
  short* BsL = &Bs[0][0] + tid * 8;

  f32x4 acc[4][4];
#pragma unroll
  for (int i = 0; i < 4; ++i)
#pragma unroll
    for (int j = 0; j < 4; ++j) acc[i][j] = (f32x4){0.f, 0.f, 0.f, 0.f};

  const int fm = wave_m * 64 + (lane & 15);   // fragment row base (im*16 added)
  const int fn = wave_n * 64 + (lane & 15);
  const int fk = (lane >> 4) * 8;             // fragment k offset

  for (int k0 = 0; k0 < K; k0 += 32) {
    stage16(Ag0 + k0, AsL);
    stage16(Ag0 + (size_t)64 * K + k0, AsL + 2048);
    stage16(Bg0 + k0, BsL);
    stage16(Bg0 + (size_t)64 * K + k0, BsL + 2048);
    __syncthreads();   // drains vmcnt(0) (compiler inserts before barrier)
    bf16x8 af[4], bf[4];
#pragma unroll
    for (int t = 0; t < 4; ++t) {
      af[t] = *(const bf16x8*)&As[fm + t * 16][fk];
      bf[t] = *(const bf16x8*)&Bs[fn + t * 16][fk];
    }
#pragma unroll
    for (int im = 0; im < 4; ++im)
#pragma unroll
      for (int jn = 0; jn < 4; ++jn)
        acc[im][jn] = __builtin_amdgcn_mfma_f32_16x16x32_bf16(af[im], bf[jn], acc[im][jn], 0, 0, 0);
    __syncthreads();   // WAR: done reading LDS before next stage
  }

  // C/D layout: col = lane&15, row = (lane>>4)*4 + reg  [m89/m91]
  const int crow = (lane >> 4) * 4, ccol = lane & 15;
#pragma unroll
  for (int im = 0; im < 4; ++im)
#pragma unroll
    for (int jn = 0; jn < 4; ++jn) {
      float* Cp = C + (size_t)(row0 + wave_m * 64 + im * 16 + crow) * ldc
                    + col0 + wave_n * 64 + jn * 16 + ccol;
#pragma unroll
      for (int r = 0; r < 4; ++r) Cp[(size_t)r * ldc] = acc[im][jn][r];
    }
}

// ---------------------------------------------------------------------------
// fp32 -> bf16 elementwise (x conversion). n multiple of 1024.
// ---------------------------------------------------------------------------
__global__ __launch_bounds__(256) void cvt_bf16(const float* __restrict__ in,
                                                __hip_bfloat16* __restrict__ out, int n) {
  int i = (blockIdx.x * 256 + threadIdx.x) * 4;
  if (i >= n) return;
  float4 v = *(const float4*)(in + i);
  union { __hip_bfloat16 h[4]; uint2 u; } pk;
  pk.h[0] = __float2bfloat16(v.x); pk.h[1] = __float2bfloat16(v.y);
  pk.h[2] = __float2bfloat16(v.z); pk.h[3] = __float2bfloat16(v.w);
  *(uint2*)(out + i) = pk.u;
}

// ---------------------------------------------------------------------------
// W [1024,1024] fp32 row-major -> Wt bf16 [N=1024][K=1024] (Wt[n][k]=W[k][n]).
// 64x64 tiles via LDS.
// ---------------------------------------------------------------------------
__global__ __launch_bounds__(256) void transposeW(const float* __restrict__ W,
                                                  __hip_bfloat16* __restrict__ Wt) {
  __shared__ float tile[64][65];
  const int tid = threadIdx.x;
  const int kt = blockIdx.y * 64, nt = blockIdx.x * 64;
  const int lr = tid >> 6, lc = tid & 63;   // 4 rows x 64 cols per pass
#pragma unroll
  for (int i = 0; i < 16; ++i) {
    int k = i * 4 + lr;
    tile[k][lc] = W[(size_t)(kt + k) * DM + nt + lc];
  }
  __syncthreads();
  // write: per i, 16 n-rows x 64 k, each thread 4 consecutive k
  const int nl = tid >> 4, k4 = (tid & 15) * 4;
#pragma unroll
  for (int i = 0; i < 4; ++i) {
    int n = i * 16 + nl;
    union { __hip_bfloat16 h[4]; uint2 u; } pk;
#pragma unroll
    for (int x = 0; x < 4; ++x) pk.h[x] = __float2bfloat16(tile[k4 + x][n]);
    *(uint2*)(Wt + (size_t)(nt + n) * DM + kt + k4) = pk.u;
  }
}

// ---------------------------------------------------------------------------
// Phase A: per (b,h,chunk) M_c[i][j] = sum_{s in chunk} k_s[i]*v_s[j].
// qkv packed [MR][3072]: q|k|v.
// ---------------------------------------------------------------------------
__global__ __launch_bounds__(256) void chunk_kv(const float* __restrict__ QKV,
                                                float* __restrict__ S) {
  const int c = blockIdx.x, h = blockIdx.y, b = blockIdx.z;
  __shared__ __align__(16) float Ks[CH][DH];
  __shared__ __align__(16) float Vs[CH][DH];
  const int tid = threadIdx.x;
  const size_t rowbase = ((size_t)(b * TSEQ + c * CH)) * QKVLD + h * DH;
#pragma unroll
  for (int it = 0; it < 4; ++it) {
    int idx = tid + 256 * it;
    int s = idx >> 4, i4 = (idx & 15) * 4;
    *(float4*)&Ks[s][i4] = *(const float4*)(QKV + rowbase + DM + (size_t)s * QKVLD + i4);
    *(float4*)&Vs[s][i4] = *(const float4*)(QKV + rowbase + 2 * DM + (size_t)s * QKVLD + i4);
  }
  __syncthreads();
  const int i0 = (tid >> 4) * 4, j0 = (tid & 15) * 4;
  float acc[4][4] = {};
  for (int s = 0; s < CH; ++s) {
    float a[4], bv[4];
#pragma unroll
    for (int x = 0; x < 4; ++x) { a[x] = Ks[s][i0 + x]; bv[x] = Vs[s][j0 + x]; }
#pragma unroll
    for (int i = 0; i < 4; ++i)
#pragma unroll
      for (int j = 0; j < 4; ++j)
        acc[i][j] = fmaf(a[i], bv[j], acc[i][j]);
  }
  float* out = S + ((size_t)((b * NHEAD + h) * NC + c)) * (DH * DH);
#pragma unroll
  for (int i = 0; i < 4; ++i) {
    float4 o = {acc[i][0], acc[i][1], acc[i][2], acc[i][3]};
    *(float4*)(out + (size_t)(i0 + i) * DH + j0) = o;
  }
}

// ---------------------------------------------------------------------------
// Phase B: exclusive prefix sum of 32 chunk states per (b,h).
// grid (16, 32): block = 256 contiguous elems of the 4096-elem state.
// ---------------------------------------------------------------------------
__global__ __launch_bounds__(256) void scan_states(float* __restrict__ S) {
  const int bh = blockIdx.y;
  float* base = S + (size_t)bh * NC * (DH * DH) + blockIdx.x * 256 + threadIdx.x;
  float run = 0.f;
  for (int c = 0; c < NC; ++c) {
    float t = base[(size_t)c * (DH * DH)];
    base[(size_t)c * (DH * DH)] = run;
    run += t;
  }
}

// ---------------------------------------------------------------------------
// Phase C: out_t = q_t @ S_c + sum_{s in chunk, s<t} (q_t.k_s) v_s.
// Writes bf16 attention output [MR][DM] (feeds final MFMA GEMM directly).
// ---------------------------------------------------------------------------
__global__ __launch_bounds__(256) void intra_attn(const float* __restrict__ QKV,
                                                  const float* __restrict__ S,
                                                  __hip_bfloat16* __restrict__ O_) {
  const int c = blockIdx.x, h = blockIdx.y, b = blockIdx.z;
  __shared__ __align__(16) float Qs[CH][DH];
  __shared__ __align__(16) float Ks[CH][DH];
  __shared__ __align__(16) float Vs[CH][DH];
  __shared__ __align__(16) float Ss[DH][DH];   // state -> then P
  const int tid = threadIdx.x;
  const size_t rowbase = ((size_t)(b * TSEQ + c * CH)) * QKVLD + h * DH;
  const float* Sb = S + ((size_t)((b * NHEAD + h) * NC + c)) * (DH * DH);
#pragma unroll
  for (int it = 0; it < 4; ++it) {
    int idx = tid + 256 * it;
    int s = idx >> 4, i4 = (idx & 15) * 4;
    size_t g = rowbase + (size_t)s * QKVLD + i4;
    *(float4*)&Qs[s][i4] = *(const float4*)(QKV + g);
    *(float4*)&Ks[s][i4] = *(const float4*)(QKV + g + DM);
    *(float4*)&Vs[s][i4] = *(const float4*)(QKV + g + 2 * DM);
    *(float4*)&Ss[s][i4] = *(const float4*)(Sb + (size_t)idx * 4);
  }
  __syncthreads();
  const int t0 = (tid >> 4) * 4, j0 = (tid & 15) * 4;

  float oacc[4][4] = {};
  for (int i = 0; i < DH; ++i) {
    float a[4], bb[4];
#pragma unroll
    for (int x = 0; x < 4; ++x) { a[x] = Qs[t0 + x][i]; bb[x] = Ss[i][j0 + x]; }
#pragma unroll
    for (int ii = 0; ii < 4; ++ii)
#pragma unroll
      for (int jj = 0; jj < 4; ++jj)
        oacc[ii][jj] = fmaf(a[ii], bb[jj], oacc[ii][jj]);
  }
  float pacc[4][4] = {};
  for (int i = 0; i < DH; ++i) {
    float a[4], bb[4];
#pragma unroll
    for (int x = 0; x < 4; ++x) { a[x] = Qs[t0 + x][i]; bb[x] = Ks[j0 + x][i]; }
#pragma unroll
    for (int ii = 0; ii < 4; ++ii)
#pragma unroll
      for (int jj = 0; jj < 4; ++jj)
        pacc[ii][jj] = fmaf(a[ii], bb[jj], pacc[ii][jj]);
  }
  __syncthreads();
#pragma unroll
  for (int ii = 0; ii < 4; ++ii)
#pragma unroll
    for (int jj = 0; jj < 4; ++jj)
      Ss[t0 + ii][j0 + jj] = (j0 + jj < t0 + ii) ? pacc[ii][jj] : 0.f;
  __syncthreads();
  for (int s = 0; s < CH; ++s) {
    float a[4], bb[4];
#pragma unroll
    for (int x = 0; x < 4; ++x) { a[x] = Ss[t0 + x][s]; bb[x] = Vs[s][j0 + x]; }
#pragma unroll
    for (int ii = 0; ii < 4; ++ii)
#pragma unroll
      for (int jj = 0; jj < 4; ++jj)
        oacc[ii][jj] = fmaf(a[ii], bb[jj], oacc[ii][jj]);
  }
  const size_t obase = ((size_t)(b * TSEQ + c * CH)) * DM + h * DH;
#pragma unroll
  for (int ii = 0; ii < 4; ++ii) {
    union { __hip_bfloat16 h[4]; uint2 u; } pk;
#pragma unroll
    for (int jj = 0; jj < 4; ++jj) pk.h[jj] = __float2bfloat16(oacc[ii][jj]);
    *(uint2*)(O_ + obase + (size_t)(t0 + ii) * DM + j0) = pk.u;
  }
}

// ---------------------------------------------------------------------------
extern "C" void kernel_launch(void* const* d_in, const int* in_sizes, int n_in,
                              void* d_out, int out_size, void* d_ws, size_t ws_size,
                              hipStream_t stream) {
  const float* x  = (const float*)d_in[0];
  const float* Wq = (const float*)d_in[1];
  const float* Wk = (const float*)d_in[2];
  const float* Wv = (const float*)d_in[3];
  const float* Wo = (const float*)d_in[4];
  float* out = (float*)d_out;

  char* ws = (char*)d_ws;
  __hip_bfloat16* xb    = (__hip_bfloat16*)ws;              ws += (size_t)MR * DM * 2;        // 8 MB
  __hip_bfloat16* WtQKV = (__hip_bfloat16*)ws;              ws += (size_t)3 * DM * DM * 2;    // 6 MB
  __hip_bfloat16* WoT   = (__hip_bfloat16*)ws;              ws += (size_t)DM * DM * 2;        // 2 MB
  float*          qkv   = (float*)ws;                       ws += (size_t)MR * QKVLD * 4;     // 48 MB
  float*          S     = (float*)ws;                       ws += (size_t)BATCH * NHEAD * NC * DH * DH * 4; // 16 MB
  __hip_bfloat16* aob   = (__hip_bfloat16*)ws;              ws += (size_t)MR * DM * 2;        // 8 MB

  // conversions
  cvt_bf16<<<(MR * DM / 4 + 255) / 256, 256, 0, stream>>>(x, xb, MR * DM);
  dim3 tg(DM / 64, DM / 64);
  transposeW<<<tg, 256, 0, stream>>>(Wq, WtQKV);
  transposeW<<<tg, 256, 0, stream>>>(Wk, WtQKV + (size_t)DM * DM);
  transposeW<<<tg, 256, 0, stream>>>(Wv, WtQKV + (size_t)2 * DM * DM);
  transposeW<<<tg, 256, 0, stream>>>(Wo, WoT);

  // fused QKV projection: [4096,1024] @ [1024,3072] -> [4096,3072]
  gemm_bf16<<<dim3(QKVLD / 128, MR / 128), 256, 0, stream>>>(
      (const short*)xb, (const short*)WtQKV, qkv, MR, QKVLD, DM, QKVLD);

  chunk_kv<<<dim3(NC, NHEAD, BATCH), 256, 0, stream>>>(qkv, S);
  scan_states<<<dim3(DH * DH / 256, BATCH * NHEAD), 256, 0, stream>>>(S);
  intra_attn<<<dim3(NC, NHEAD, BATCH), 256, 0, stream>>>(qkv, S, aob);

  // output projection: [4096,1024] @ [1024,1024] -> [4096,1024]
  gemm_bf16<<<dim3(DM / 128, MR / 128), 256, 0, stream>>>(
      (const short*)aob, (const short*)WoT, out, MR, DM, DM, DM);
}

// Round 3
// 170.217 us; speedup vs baseline: 3.6933x; 1.4173x over previous
//
#include <hip/hip_runtime.h>
#include <hip/hip_bf16.h>

// Problem constants (QuadraticAttention): B=2, T=2048, D_MODEL=1024, H=16, d=64
#define TSEQ   2048
#define DM     1024
#define NHEAD  16
#define DH     64
#define BATCH  2
#define MR     (BATCH * TSEQ)   // 4096 rows
#define CH     64               // attention chunk length
#define NC     (TSEQ / CH)      // 32 chunks per sequence
#define QKVLD  (3 * DM)         // 3072: q|k|v packed per token row
#define LP     72               // padded LDS row stride (bf16), 144 B, 16B-aligned

typedef __attribute__((ext_vector_type(8))) short bf16x8;
typedef __attribute__((ext_vector_type(4))) float f32x4;

__device__ __forceinline__ short f2bf(float x) {
  __hip_bfloat16 h = __float2bfloat16(x);
  return *reinterpret_cast<short*>(&h);
}

// ---------------------------------------------------------------------------
// async global->LDS, 16 bytes per lane (wave-uniform base + lane*16).
// ---------------------------------------------------------------------------
__device__ __forceinline__ void stage16(const void* g, void* l) {
  __builtin_amdgcn_global_load_lds(
      (const __attribute__((address_space(1))) void*)g,
      (__attribute__((address_space(3))) void*)l, 16, 0, 0);
}

__device__ __forceinline__ void store_elem(float v, float* p) { *p = v; }
__device__ __forceinline__ void store_elem(float v, __hip_bfloat16* p) { *p = __float2bfloat16(v); }

// ---------------------------------------------------------------------------
// bf16 MFMA GEMM (m97 structure): C[M,N] = A[M,K] @ B[K,N].
// A: bf16 row-major [M,K]. Bt: bf16 [N,K] (B transposed). OutT = float or bf16.
// 128x128 tile, BK=32, 256 threads = 4 waves (2x2), 4x4 MFMA tiles per wave.
// ---------------------------------------------------------------------------
template <typename OutT>
__global__ __launch_bounds__(256) void gemm_bf16(const short* __restrict__ A,
                                                 const short* __restrict__ Bt,
                                                 OutT* __restrict__ C,
                                                 int M, int N, int K, int ldc) {
  __shared__ short As[128][32];  // [m][k]  8 KB
  __shared__ short Bs[128][32];  // [n][k]  8 KB
  const int tid = threadIdx.x;
  const int lane = tid & 63, wid = tid >> 6;
  const int wave_m = wid >> 1, wave_n = wid & 1;
  const int row0 = blockIdx.y * 128, col0 = blockIdx.x * 128;

  const int sr = tid >> 2, sk = (tid & 3) * 8;
  const short* Ag0 = A + (size_t)(row0 + sr) * K + sk;
  const short* Bg0 = Bt + (size_t)(col0 + sr) * K + sk;
  short* AsL = &As[0][0] + tid * 8;
  short* BsL = &Bs[0][0] + tid * 8;

  f32x4 acc[4][4];
#pragma unroll
  for (int i = 0; i < 4; ++i)
#pragma unroll
    for (int j = 0; j < 4; ++j) acc[i][j] = (f32x4){0.f, 0.f, 0.f, 0.f};

  const int fm = wave_m * 64 + (lane & 15);
  const int fn = wave_n * 64 + (lane & 15);
  const int fk = (lane >> 4) * 8;

  for (int k0 = 0; k0 < K; k0 += 32) {
    stage16(Ag0 + k0, AsL);
    stage16(Ag0 + (size_t)64 * K + k0, AsL + 2048);
    stage16(Bg0 + k0, BsL);
    stage16(Bg0 + (size_t)64 * K + k0, BsL + 2048);
    __syncthreads();
    bf16x8 af[4], bf[4];
#pragma unroll
    for (int t = 0; t < 4; ++t) {
      af[t] = *(const bf16x8*)&As[fm + t * 16][fk];
      bf[t] = *(const bf16x8*)&Bs[fn + t * 16][fk];
    }
#pragma unroll
    for (int im = 0; im < 4; ++im)
#pragma unroll
      for (int jn = 0; jn < 4; ++jn)
        acc[im][jn] = __builtin_amdgcn_mfma_f32_16x16x32_bf16(af[im], bf[jn], acc[im][jn], 0, 0, 0);
    __syncthreads();
  }

  const int crow = (lane >> 4) * 4, ccol = lane & 15;
#pragma unroll
  for (int im = 0; im < 4; ++im)
#pragma unroll
    for (int jn = 0; jn < 4; ++jn) {
      OutT* Cp = C + (size_t)(row0 + wave_m * 64 + im * 16 + crow) * ldc
                   + col0 + wave_n * 64 + jn * 16 + ccol;
#pragma unroll
      for (int r = 0; r < 4; ++r) store_elem(acc[im][jn][r], Cp + (size_t)r * ldc);
    }
}

// ---------------------------------------------------------------------------
// fp32 -> bf16 elementwise (x conversion).
// ---------------------------------------------------------------------------
__global__ __launch_bounds__(256) void cvt_bf16(const float* __restrict__ in,
                                                __hip_bfloat16* __restrict__ out, int n) {
  int i = (blockIdx.x * 256 + threadIdx.x) * 4;
  if (i >= n) return;
  float4 v = *(const float4*)(in + i);
  union { __hip_bfloat16 h[4]; uint2 u; } pk;
  pk.h[0] = __float2bfloat16(v.x); pk.h[1] = __float2bfloat16(v.y);
  pk.h[2] = __float2bfloat16(v.z); pk.h[3] = __float2bfloat16(v.w);
  *(uint2*)(out + i) = pk.u;
}

// ---------------------------------------------------------------------------
// All 4 weight transposes in one launch: Wt[z][n][k] = W_z[k][n], bf16 out.
// grid (16,16,4), 64x64 tiles via LDS.
// ---------------------------------------------------------------------------
__global__ __launch_bounds__(256) void transposeW4(const float* __restrict__ W0,
                                                   const float* __restrict__ W1,
                                                   const float* __restrict__ W2,
                                                   const float* __restrict__ W3,
                                                   __hip_bfloat16* __restrict__ Wt) {
  const float* W = blockIdx.z == 0 ? W0 : blockIdx.z == 1 ? W1 : blockIdx.z == 2 ? W2 : W3;
  __hip_bfloat16* out = Wt + (size_t)blockIdx.z * DM * DM;
  __shared__ float tile[64][65];
  const int tid = threadIdx.x;
  const int kt = blockIdx.y * 64, nt = blockIdx.x * 64;
  const int lr = tid >> 6, lc = tid & 63;
#pragma unroll
  for (int i = 0; i < 16; ++i) {
    int k = i * 4 + lr;
    tile[k][lc] = W[(size_t)(kt + k) * DM + nt + lc];
  }
  __syncthreads();
  const int nl = tid >> 4, k4 = (tid & 15) * 4;
#pragma unroll
  for (int i = 0; i < 4; ++i) {
    int n = i * 16 + nl;
    union { __hip_bfloat16 h[4]; uint2 u; } pk;
#pragma unroll
    for (int x = 0; x < 4; ++x) pk.h[x] = __float2bfloat16(tile[k4 + x][n]);
    *(uint2*)(out + (size_t)(nt + n) * DM + kt + k4) = pk.u;
  }
}

// ---------------------------------------------------------------------------
// Phase A (MFMA): Mc^T[j][i] = sum_{s in chunk} V[s][j] * K[s][i], fp32 out.
// A-frag = Vt[j][s], B-frag = Kt[i][s] (both transposed in LDS).
// One block per (c,h,b); 4 waves, each a 16-row strip of the 64x64 output.
// ---------------------------------------------------------------------------
__global__ __launch_bounds__(256) void chunk_kv(const __hip_bfloat16* __restrict__ QKV,
                                                float* __restrict__ Mc) {
  const int c = blockIdx.x, h = blockIdx.y, b = blockIdx.z;
  __shared__ short Kt[DH][LP];   // [i][s]
  __shared__ short Vt[DH][LP];   // [j][s]
  const int tid = threadIdx.x;
  const int lane = tid & 63, w = tid >> 6;
  const int r = tid >> 2, q16 = (tid & 3) * 16;
  const short* qkv = (const short*)QKV;
  const size_t grow = ((size_t)(b * TSEQ + c * CH + r)) * QKVLD + h * DH;
  short kk[16], vv[16];
  *(bf16x8*)&kk[0] = *(const bf16x8*)(qkv + grow + DM + q16);
  *(bf16x8*)&kk[8] = *(const bf16x8*)(qkv + grow + DM + q16 + 8);
  *(bf16x8*)&vv[0] = *(const bf16x8*)(qkv + grow + 2 * DM + q16);
  *(bf16x8*)&vv[8] = *(const bf16x8*)(qkv + grow + 2 * DM + q16 + 8);
#pragma unroll
  for (int j = 0; j < 16; ++j) {
    Kt[q16 + j][r] = kk[j];
    Vt[q16 + j][r] = vv[j];
  }
  __syncthreads();

  const int m = lane & 15, q = lane >> 4;
  bf16x8 af[2];
  af[0] = *(const bf16x8*)&Vt[16 * w + m][q * 8];
  af[1] = *(const bf16x8*)&Vt[16 * w + m][q * 8 + 32];
  f32x4 acc[4];
#pragma unroll
  for (int ct = 0; ct < 4; ++ct) acc[ct] = (f32x4){0.f, 0.f, 0.f, 0.f};
#pragma unroll
  for (int ct = 0; ct < 4; ++ct) {
    bf16x8 b0 = *(const bf16x8*)&Kt[ct * 16 + m][q * 8];
    bf16x8 b1 = *(const bf16x8*)&Kt[ct * 16 + m][q * 8 + 32];
    acc[ct] = __builtin_amdgcn_mfma_f32_16x16x32_bf16(af[0], b0, acc[ct], 0, 0, 0);
    acc[ct] = __builtin_amdgcn_mfma_f32_16x16x32_bf16(af[1], b1, acc[ct], 0, 0, 0);
  }
  float* out = Mc + ((size_t)((b * NHEAD + h) * NC + c)) * (DH * DH);
#pragma unroll
  for (int ct = 0; ct < 4; ++ct)
#pragma unroll
    for (int rr = 0; rr < 4; ++rr) {
      int row = 16 * w + q * 4 + rr, col = ct * 16 + m;
      out[(size_t)row * DH + col] = acc[ct][rr];
    }
}

// ---------------------------------------------------------------------------
// Phase B: exclusive prefix sum over 32 chunks (fp32 in, bf16 out).
// grid (16, 32): each thread owns one of the 4096 state elements.
// ---------------------------------------------------------------------------
__global__ __launch_bounds__(256) void scan_states(const float* __restrict__ Mc,
                                                   __hip_bfloat16* __restrict__ Spre) {
  const int bh = blockIdx.y;
  const size_t off = (size_t)bh * NC * (DH * DH) + blockIdx.x * 256 + threadIdx.x;
  const float* src = Mc + off;
  __hip_bfloat16* dst = Spre + off;
  float run = 0.f;
  for (int c = 0; c < NC; ++c) {
    dst[(size_t)c * (DH * DH)] = __float2bfloat16(run);
    run += src[(size_t)c * (DH * DH)];
  }
}

// ---------------------------------------------------------------------------
// Phase C (MFMA): out = Q @ S + mask(Q @ K^T) @ V  per (b,h,chunk).
// Qs: [t][i] natural (reused for masked P [t][s]); Ks: [s][i] natural;
// Vt: [j][s]; St: [j][i] (= S^T as stored by scan). bf16 out.
// LDS 4*64*72*2 = 36 KB -> 4 blocks/CU.
// ---------------------------------------------------------------------------
__global__ __launch_bounds__(256) void intra_attn(const __hip_bfloat16* __restrict__ QKV,
                                                  const __hip_bfloat16* __restrict__ Spre,
                                                  __hip_bfloat16* __restrict__ O_) {
  const int c = blockIdx.x, h = blockIdx.y, b = blockIdx.z;
  __shared__ short Qs[CH][LP];
  __shared__ short Ks[CH][LP];
  __shared__ short Vt[DH][LP];
  __shared__ short St[DH][LP];
  const int tid = threadIdx.x;
  const int lane = tid & 63, w = tid >> 6;
  const int r = tid >> 2, q16 = (tid & 3) * 16;
  const short* qkv = (const short*)QKV;
  const size_t grow = ((size_t)(b * TSEQ + c * CH + r)) * QKVLD + h * DH;
  *(bf16x8*)&Qs[r][q16]     = *(const bf16x8*)(qkv + grow + q16);
  *(bf16x8*)&Qs[r][q16 + 8] = *(const bf16x8*)(qkv + grow + q16 + 8);
  *(bf16x8*)&Ks[r][q16]     = *(const bf16x8*)(qkv + grow + DM + q16);
  *(bf16x8*)&Ks[r][q16 + 8] = *(const bf16x8*)(qkv + grow + DM + q16 + 8);
  const short* Sg = (const short*)Spre + ((size_t)((b * NHEAD + h) * NC + c)) * (DH * DH);
  *(bf16x8*)&St[r][q16]     = *(const bf16x8*)(Sg + r * DH + q16);
  *(bf16x8*)&St[r][q16 + 8] = *(const bf16x8*)(Sg + r * DH + q16 + 8);
  short vv[16];
  *(bf16x8*)&vv[0] = *(const bf16x8*)(qkv + grow + 2 * DM + q16);
  *(bf16x8*)&vv[8] = *(const bf16x8*)(qkv + grow + 2 * DM + q16 + 8);
#pragma unroll
  for (int j = 0; j < 16; ++j) Vt[q16 + j][r] = vv[j];
  __syncthreads();

  const int m = lane & 15, q = lane >> 4;
  bf16x8 af[2];
  af[0] = *(const bf16x8*)&Qs[16 * w + m][q * 8];
  af[1] = *(const bf16x8*)&Qs[16 * w + m][q * 8 + 32];
  f32x4 acc[4], pacc[4];
#pragma unroll
  for (int ct = 0; ct < 4; ++ct) {
    acc[ct] = (f32x4){0.f, 0.f, 0.f, 0.f};
    pacc[ct] = (f32x4){0.f, 0.f, 0.f, 0.f};
  }
  // GEMM1: acc = Q @ S   (B-frag from St[j][i])
  // GEMM2: pacc = Q @ K^T (B-frag from Ks[s][i]) — shares af
#pragma unroll
  for (int ct = 0; ct < 4; ++ct) {
    bf16x8 s0 = *(const bf16x8*)&St[ct * 16 + m][q * 8];
    bf16x8 s1 = *(const bf16x8*)&St[ct * 16 + m][q * 8 + 32];
    acc[ct] = __builtin_amdgcn_mfma_f32_16x16x32_bf16(af[0], s0, acc[ct], 0, 0, 0);
    acc[ct] = __builtin_amdgcn_mfma_f32_16x16x32_bf16(af[1], s1, acc[ct], 0, 0, 0);
    bf16x8 k0 = *(const bf16x8*)&Ks[ct * 16 + m][q * 8];
    bf16x8 k1 = *(const bf16x8*)&Ks[ct * 16 + m][q * 8 + 32];
    pacc[ct] = __builtin_amdgcn_mfma_f32_16x16x32_bf16(af[0], k0, pacc[ct], 0, 0, 0);
    pacc[ct] = __builtin_amdgcn_mfma_f32_16x16x32_bf16(af[1], k1, pacc[ct], 0, 0, 0);
  }
  __syncthreads();   // all waves done reading Qs (af already in regs)
  // strict causal mask (keep s < t), write P as bf16 into Qs storage [t][s]
#pragma unroll
  for (int ct = 0; ct < 4; ++ct) {
    int col = ct * 16 + m;
#pragma unroll
    for (int rr = 0; rr < 4; ++rr) {
      int row = 16 * w + q * 4 + rr;
      float pv = (col < row) ? pacc[ct][rr] : 0.f;
      Qs[row][col] = f2bf(pv);
    }
  }
  __syncthreads();
  // GEMM3: acc += P @ V   (A-frag from Qs(P)[t][s], B-frag from Vt[j][s])
  bf16x8 pf[2];
  pf[0] = *(const bf16x8*)&Qs[16 * w + m][q * 8];
  pf[1] = *(const bf16x8*)&Qs[16 * w + m][q * 8 + 32];
#pragma unroll
  for (int ct = 0; ct < 4; ++ct) {
    bf16x8 v0 = *(const bf16x8*)&Vt[ct * 16 + m][q * 8];
    bf16x8 v1 = *(const bf16x8*)&Vt[ct * 16 + m][q * 8 + 32];
    acc[ct] = __builtin_amdgcn_mfma_f32_16x16x32_bf16(pf[0], v0, acc[ct], 0, 0, 0);
    acc[ct] = __builtin_amdgcn_mfma_f32_16x16x32_bf16(pf[1], v1, acc[ct], 0, 0, 0);
  }
  __hip_bfloat16* Ob = O_ + ((size_t)(b * TSEQ + c * CH)) * DM + h * DH;
#pragma unroll
  for (int ct = 0; ct < 4; ++ct)
#pragma unroll
    for (int rr = 0; rr < 4; ++rr) {
      int row = 16 * w + q * 4 + rr, col = ct * 16 + m;
      Ob[(size_t)row * DM + col] = __float2bfloat16(acc[ct][rr]);
    }
}

// ---------------------------------------------------------------------------
extern "C" void kernel_launch(void* const* d_in, const int* in_sizes, int n_in,
                              void* d_out, int out_size, void* d_ws, size_t ws_size,
                              hipStream_t stream) {
  const float* x  = (const float*)d_in[0];
  const float* Wq = (const float*)d_in[1];
  const float* Wk = (const float*)d_in[2];
  const float* Wv = (const float*)d_in[3];
  const float* Wo = (const float*)d_in[4];
  float* out = (float*)d_out;

  char* ws = (char*)d_ws;
  __hip_bfloat16* xb    = (__hip_bfloat16*)ws;  ws += (size_t)MR * DM * 2;              // 8 MB
  __hip_bfloat16* WtAll = (__hip_bfloat16*)ws;  ws += (size_t)4 * DM * DM * 2;          // 8 MB
  __hip_bfloat16* qkvb  = (__hip_bfloat16*)ws;  ws += (size_t)MR * QKVLD * 2;           // 24 MB
  float*          Mc    = (float*)ws;           ws += (size_t)BATCH * NHEAD * NC * DH * DH * 4; // 16 MB
  __hip_bfloat16* Spre  = (__hip_bfloat16*)ws;  ws += (size_t)BATCH * NHEAD * NC * DH * DH * 2; // 8 MB
  __hip_bfloat16* aob   = (__hip_bfloat16*)ws;  ws += (size_t)MR * DM * 2;              // 8 MB

  cvt_bf16<<<(MR * DM / 4 + 255) / 256, 256, 0, stream>>>(x, xb, MR * DM);
  transposeW4<<<dim3(DM / 64, DM / 64, 4), 256, 0, stream>>>(Wq, Wk, Wv, Wo, WtAll);

  // fused QKV projection: [4096,1024] @ [1024,3072] -> bf16 [4096,3072]
  gemm_bf16<__hip_bfloat16><<<dim3(QKVLD / 128, MR / 128), 256, 0, stream>>>(
      (const short*)xb, (const short*)WtAll, qkvb, MR, QKVLD, DM, QKVLD);

  chunk_kv<<<dim3(NC, NHEAD, BATCH), 256, 0, stream>>>(qkvb, Mc);
  scan_states<<<dim3(DH * DH / 256, BATCH * NHEAD), 256, 0, stream>>>(Mc, Spre);
  intra_attn<<<dim3(NC, NHEAD, BATCH), 256, 0, stream>>>(qkvb, Spre, aob);

  // output projection: [4096,1024] @ [1024,1024] -> fp32 [4096,1024]
  gemm_bf16<float><<<dim3(DM / 128, MR / 128), 256, 0, stream>>>(
      (const short*)aob, (const short*)(WtAll + (size_t)3 * DM * DM), out, MR, DM, DM, DM);
}